// Round 1
// baseline (2138.206 us; speedup 1.0000x reference)
//
#include <hip/hip_runtime.h>
#include <math.h>

// Problem constants
#define BB 8
#define LL 8192
#define DD 512
#define NROWS (BB * LL)  // 65536

// d_out layout (floats), outputs concatenated in return order
#define OUT_COMP   0
#define OUT_MASK   33554432
#define OUT_BHARD  33619968
#define OUT_P      33685504
#define OUT_PCOMP  33751040
#define OUT_LOSS   33816576

// ws layout (bytes)
#define WS_FIXLIST 0         // 65536 * 4
#define WS_FIXCNT  262144    // 4
#define WS_COUNTS  262148    // 8 * 4
#define WS_SUMP    262180    // 8 * 4
#define WS_SEL     262212    // 65536 * 4

#define FIX_CAP 65536
#define FIX_TAU 1e-4f

// ---------------------------------------------------------------------------
// Pass 1/2: row GEMM (M=65536, N=512, K=512), 32 rows per block, 256 threads.
// PASS==1: C = x*Wk^T, normalize rows, store to kbuf.
// PASS==2: C = x*Wq^T, compute |q|, cos = (q . kbuf[r-1]) / |q|, write p/b_hard,
//          log |cos|<tau rows to fixup list.
// Thread map: tc = tid&31 (cols e = tc+32j, j<16), tr = tid>>5 (rows m = tr+8i, i<4)
// ---------------------------------------------------------------------------
template <int PASS>
__global__ __launch_bounds__(256) void rowgemm(
    const float* __restrict__ x, const float* __restrict__ W,
    float* __restrict__ kbuf, float* __restrict__ dout,
    int* __restrict__ fixlist, int* __restrict__ fixcnt) {
  __shared__ float xs[32][16];
  __shared__ float wsh[512][17];  // pitch 17: conflict-free reads across tc

  const int tid = threadIdx.x;
  const int tc = tid & 31;
  const int tr = tid >> 5;
  const long r0 = (long)blockIdx.x * 32;

  if (PASS == 1 && blockIdx.x == 0 && tid == 0) *fixcnt = 0;

  float acc[4][16];
#pragma unroll
  for (int i = 0; i < 4; ++i)
#pragma unroll
    for (int j = 0; j < 16; ++j) acc[i][j] = 0.0f;

  for (int k0 = 0; k0 < 512; k0 += 16) {
    // x tile: 32 rows x 16 cols = 128 float4, threads 0..127
    if (tid < 128) {
      int row = tid >> 2, q = tid & 3;
      float4 v = *(const float4*)(x + (r0 + row) * 512 + k0 + q * 4);
      *(float4*)&xs[row][q * 4] = v;
    }
    // W tile: 512 rows x 16 cols, each thread 8 rows' quads
    {
      int q = tid & 3, e0 = tid >> 2;
#pragma unroll
      for (int i = 0; i < 8; ++i) {
        int e = e0 + i * 64;
        float4 v = *(const float4*)(W + (long)e * 512 + k0 + q * 4);
        wsh[e][q * 4 + 0] = v.x;
        wsh[e][q * 4 + 1] = v.y;
        wsh[e][q * 4 + 2] = v.z;
        wsh[e][q * 4 + 3] = v.w;
      }
    }
    __syncthreads();
#pragma unroll
    for (int kk = 0; kk < 16; ++kk) {
      float xv[4], wv[16];
#pragma unroll
      for (int i = 0; i < 4; ++i) xv[i] = xs[tr + 8 * i][kk];
#pragma unroll
      for (int j = 0; j < 16; ++j) wv[j] = wsh[tc + 32 * j][kk];
#pragma unroll
      for (int i = 0; i < 4; ++i)
#pragma unroll
        for (int j = 0; j < 16; ++j) acc[i][j] = fmaf(xv[i], wv[j], acc[i][j]);
    }
    __syncthreads();
  }

#pragma unroll
  for (int i = 0; i < 4; ++i) {
    const long r = r0 + tr + 8 * i;
    // sum of squares of this row (across j locally, then across tc lanes)
    float ss = 0.0f;
#pragma unroll
    for (int j = 0; j < 16; ++j) ss = fmaf(acc[i][j], acc[i][j], ss);
#pragma unroll
    for (int off = 1; off < 32; off <<= 1) ss += __shfl_xor(ss, off, 64);
    float nrm = fmaxf(sqrtf(ss), 1e-12f);
    float inv = 1.0f / nrm;

    if (PASS == 1) {
#pragma unroll
      for (int j = 0; j < 16; ++j)
        kbuf[r * 512 + tc + 32 * j] = acc[i][j] * inv;
    } else {
      const int l = (int)(r & (LL - 1));
      float p, cosv = 0.0f;
      if (l != 0) {
        float dot = 0.0f;
        const float* kp = kbuf + (r - 1) * 512;
#pragma unroll
        for (int j = 0; j < 16; ++j) dot = fmaf(acc[i][j], kp[tc + 32 * j], dot);
#pragma unroll
        for (int off = 1; off < 32; off <<= 1) dot += __shfl_xor(dot, off, 64);
        cosv = dot * inv;  // kbuf rows already normalized
        float s = 1.0f - cosv;
        p = 0.5f * s;
        p = fminf(fmaxf(p, 0.0f), 1.0f);
      } else {
        p = 1.0f;
      }
      float bh = (p >= 0.5f) ? 1.0f : 0.0f;
      if (tc == 0) {
        dout[OUT_P + r] = p;
        dout[OUT_BHARD + r] = bh;
        if (l != 0 && fabsf(cosv) < FIX_TAU) {
          int idx = atomicAdd(fixcnt, 1);
          if (idx < FIX_CAP) fixlist[idx] = (int)r;
        }
      }
    }
  }
}

// ---------------------------------------------------------------------------
// Pass 2b: f64 recompute of borderline rows (expected ~120 rows).
// ---------------------------------------------------------------------------
__global__ __launch_bounds__(256) void fixup(
    const float* __restrict__ x, const float* __restrict__ Wq,
    const float* __restrict__ Wk, float* __restrict__ dout,
    const int* __restrict__ fixlist, const int* __restrict__ fixcnt) {
  __shared__ float xr[512], xp[512];
  __shared__ double red[3][256];
  const int t = threadIdx.x;
  int n = *fixcnt;
  if (n > FIX_CAP) n = FIX_CAP;

  for (int idx = blockIdx.x; idx < n; idx += gridDim.x) {
    const int r = fixlist[idx];  // guaranteed l != 0
    for (int d = t; d < 512; d += 256) {
      xr[d] = x[(long)r * 512 + d];
      xp[d] = x[(long)(r - 1) * 512 + d];
    }
    __syncthreads();
    double ssq = 0.0, ssk = 0.0, dot = 0.0;
    for (int e = t; e < 512; e += 256) {
      const float* wq = Wq + (long)e * 512;
      const float* wk = Wk + (long)e * 512;
      double q = 0.0, k = 0.0;
      for (int d = 0; d < 512; ++d) {
        q = fma((double)xr[d], (double)wq[d], q);
        k = fma((double)xp[d], (double)wk[d], k);
      }
      ssq += q * q;
      ssk += k * k;
      dot += q * k;
    }
    red[0][t] = ssq;
    red[1][t] = ssk;
    red[2][t] = dot;
    __syncthreads();
    for (int s = 128; s > 0; s >>= 1) {
      if (t < s) {
        red[0][t] += red[0][t + s];
        red[1][t] += red[1][t + s];
        red[2][t] += red[2][t + s];
      }
      __syncthreads();
    }
    if (t == 0) {
      double nq = sqrt(red[0][0]);
      double nk = sqrt(red[1][0]);
      if (nq < 1e-12) nq = 1e-12;
      if (nk < 1e-12) nk = 1e-12;
      double cosd = red[2][0] / (nq * nk);
      // emulate reference f32 downstream arithmetic
      float c = (float)cosd;
      float p = 0.5f * (1.0f - c);
      p = fminf(fmaxf(p, 0.0f), 1.0f);
      dout[OUT_P + r] = p;
      dout[OUT_BHARD + r] = (p >= 0.5f) ? 1.0f : 0.0f;
    }
    __syncthreads();
  }
}

// ---------------------------------------------------------------------------
// Pass 3: per-batch scan of b_hard -> positions, comp_mask, p_compressed, sel.
// 8 blocks (one per batch), 256 threads, 32 elements per thread.
// ---------------------------------------------------------------------------
__global__ __launch_bounds__(256) void scanb(
    float* __restrict__ dout, int* __restrict__ sel,
    int* __restrict__ counts, float* __restrict__ sump) {
  __shared__ int ssum[256];
  __shared__ float spsum[256];
  __shared__ int stotal;
  const int b = blockIdx.x;
  const int t = threadIdx.x;
  const long base = (long)b * LL;

  int cnt = 0;
  float psum = 0.0f;
  for (int j = 0; j < 32; ++j) {
    int l = t * 32 + j;
    float bh = dout[OUT_BHARD + base + l];
    float pv = dout[OUT_P + base + l];
    cnt += (bh > 0.5f) ? 1 : 0;
    psum += pv;
  }
  ssum[t] = cnt;
  spsum[t] = psum;
  __syncthreads();
  if (t == 0) {
    int run = 0;
    for (int i = 0; i < 256; ++i) {
      int c = ssum[i];
      ssum[i] = run;  // exclusive prefix
      run += c;
    }
    stotal = run;
  }
  __syncthreads();
  const int total = stotal;
  for (int s = 128; s > 0; s >>= 1) {
    if (t < s) spsum[t] += spsum[t + s];
    __syncthreads();
  }
  if (t == 0) {
    counts[b] = total;
    sump[b] = spsum[0];
  }
  // mask + zero p_compressed
  for (int j = 0; j < 32; ++j) {
    int l = t * 32 + j;
    dout[OUT_MASK + base + l] = (l < total) ? 1.0f : 0.0f;
    dout[OUT_PCOMP + base + l] = 0.0f;
  }
  __syncthreads();
  // scatter p and selected indices
  int pos = ssum[t];
  for (int j = 0; j < 32; ++j) {
    int l = t * 32 + j;
    float bh = dout[OUT_BHARD + base + l];
    if (bh > 0.5f) {
      dout[OUT_PCOMP + base + pos] = dout[OUT_P + base + l];
      sel[base + pos] = l;
      ++pos;
    }
  }
}

// ---------------------------------------------------------------------------
// Pass 4: ratio loss (scalar).
// ---------------------------------------------------------------------------
__global__ void lossk(float* __restrict__ dout, const int* __restrict__ counts,
                      const float* __restrict__ sump) {
  if (threadIdx.x == 0 && blockIdx.x == 0) {
    float fc = 0.0f, gs = 0.0f;
    for (int b = 0; b < BB; ++b) {
      fc += (float)counts[b];
      gs += sump[b];
    }
    float F = fc / (float)NROWS;
    float G = gs / (float)NROWS;
    float loss = 1.2f * (5.0f * F * G + (1.0f - F) * (1.0f - G));
    dout[OUT_LOSS] = loss;
  }
}

// ---------------------------------------------------------------------------
// Pass 5: emit compressed rows (overwrites the kbuf scratch region of d_out).
// One block per output row j, 128 threads x float4 = 512 floats.
// ---------------------------------------------------------------------------
__global__ __launch_bounds__(128) void emit(
    const float* __restrict__ x, float* __restrict__ dout,
    const int* __restrict__ sel, const int* __restrict__ counts) {
  const long bid = blockIdx.x;
  const int b = (int)(bid >> 13);
  const int j = (int)(bid & (LL - 1));
  const int cnt = counts[b];
  float4 v = make_float4(0.0f, 0.0f, 0.0f, 0.0f);
  if (j < cnt) {
    const int l = sel[((long)b << 13) + j];
    v = *(const float4*)(x + (((long)b << 13) + l) * 512 + threadIdx.x * 4);
  }
  *(float4*)(dout + OUT_COMP + (((long)b << 13) + j) * 512 + threadIdx.x * 4) = v;
}

// ---------------------------------------------------------------------------
extern "C" void kernel_launch(void* const* d_in, const int* in_sizes, int n_in,
                              void* d_out, int out_size, void* d_ws,
                              size_t ws_size, hipStream_t stream) {
  const float* x = (const float*)d_in[0];
  const float* Wq = (const float*)d_in[1];
  const float* Wk = (const float*)d_in[2];
  float* out = (float*)d_out;
  char* ws = (char*)d_ws;

  int* fixlist = (int*)(ws + WS_FIXLIST);
  int* fixcnt = (int*)(ws + WS_FIXCNT);
  int* counts = (int*)(ws + WS_COUNTS);
  float* sump = (float*)(ws + WS_SUMP);
  int* sel = (int*)(ws + WS_SEL);

  // Stage normalized K in d_out's compressed region (134 MB); emit() fully
  // overwrites it at the end.
  float* kbuf = out + OUT_COMP;

  rowgemm<1><<<NROWS / 32, 256, 0, stream>>>(x, Wk, kbuf, out, fixlist, fixcnt);
  rowgemm<2><<<NROWS / 32, 256, 0, stream>>>(x, Wq, kbuf, out, fixlist, fixcnt);
  fixup<<<512, 256, 0, stream>>>(x, Wq, Wk, out, fixlist, fixcnt);
  scanb<<<BB, 256, 0, stream>>>(out, sel, counts, sump);
  lossk<<<1, 64, 0, stream>>>(out, counts, sump);
  emit<<<NROWS, 128, 0, stream>>>(x, out, sel, counts);
}

// Round 2
// 1385.204 us; speedup vs baseline: 1.5436x; 1.5436x over previous
//
#include <hip/hip_runtime.h>
#include <hip/hip_bf16.h>
#include <math.h>

// Problem constants
#define BB 8
#define LL 8192
#define DD 512
#define NROWS (BB * LL)  // 65536

// d_out layout (floats), outputs concatenated in return order
#define OUT_COMP   0
#define OUT_MASK   33554432
#define OUT_BHARD  33619968
#define OUT_P      33685504
#define OUT_PCOMP  33751040
#define OUT_LOSS   33816576

// ws layout (bytes)
#define WS_FIXLIST 0         // 65536 * 4
#define WS_FIXCNT  262144    // 4
#define WS_COUNTS  262148    // 8 * 4
#define WS_SUMP    262180    // 8 * 4
#define WS_SEL     262212    // 65536 * 4 -> ends 524356
#define WS_WQH     524416    // 512 KB each, 16B aligned
#define WS_WQL     1048704
#define WS_WKH     1572992
#define WS_WKL     2097280   // end ~2.62 MB

#define FIX_CAP 65536
#define FIX_TAU 5e-4f

typedef __attribute__((ext_vector_type(8))) short short8;
typedef __attribute__((ext_vector_type(4))) float f32x4;

static __device__ __forceinline__ short bf16_hi(float x) {
  __hip_bfloat16 h = __float2bfloat16(x);
  return __builtin_bit_cast(short, h);
}
static __device__ __forceinline__ float bf16_back(short s) {
  __hip_bfloat16 h = __builtin_bit_cast(__hip_bfloat16, s);
  return __bfloat162float(h);
}

// ---------------------------------------------------------------------------
// Pass 0: split Wq, Wk into bf16 hi/lo arrays, stored in MFMA fragment-chunk
// order: chunk c = kt*2048 + nb*64 + l, where l=(kblk<<4)|n encodes the lane
// that will consume it; chunk holds W[e=nb*16+n][d = kt*32+kblk*8 .. +8].
// This makes GEMM B-staging loads perfectly lane-sequential.
// ---------------------------------------------------------------------------
__global__ __launch_bounds__(256) void wsplit(
    const float* __restrict__ Wq, const float* __restrict__ Wk,
    short* __restrict__ wqh, short* __restrict__ wql,
    short* __restrict__ wkh, short* __restrict__ wkl,
    int* __restrict__ fixcnt) {
  if (blockIdx.x == 0 && threadIdx.x == 0) *fixcnt = 0;
  const int b = blockIdx.x;           // 256 blocks: 128 per matrix
  const int m = b >> 7;               // 0 = Wq, 1 = Wk
  const int c = ((b & 127) << 8) + threadIdx.x;  // chunk id 0..32767
  const int kt = c >> 11;
  const int nb = (c >> 6) & 31;
  const int l = c & 63;
  const int e = nb * 16 + (l & 15);
  const int d0 = kt * 32 + (l >> 4) * 8;
  const float* src = (m ? Wk : Wq) + (long)e * 512 + d0;
  short* dh = (m ? wkh : wqh) + (long)c * 8;
  short* dl = (m ? wkl : wql) + (long)c * 8;
  float4 v0 = *(const float4*)src;
  float4 v1 = *(const float4*)(src + 4);
  float av[8] = {v0.x, v0.y, v0.z, v0.w, v1.x, v1.y, v1.z, v1.w};
  short8 hi, lo;
#pragma unroll
  for (int j = 0; j < 8; ++j) {
    short h = bf16_hi(av[j]);
    hi[j] = h;
    lo[j] = bf16_hi(av[j] - bf16_back(h));
  }
  *(short8*)dh = hi;
  *(short8*)dl = lo;
}

// ---------------------------------------------------------------------------
// Pass 1/2: split-bf16 MFMA GEMM, C = x * W^T (65536x512 @ 512x512).
// Block: 64 rows x 512 cols, 4 waves (wave w -> cols w*128..+127).
// BK=32 (one 16x16x32 K-step), 16 k-iterations. Three pairings per step:
// hi*hi + lo*hi + hi*lo (lo*lo dropped, ~1e-5 cos error, fixup covers it).
// PASS 1: normalize rows -> kbuf.  PASS 2: cos with kbuf[r-1] -> p, b_hard.
// Fragment layouts per guide (m89-verified): A[m=lane&15][k=(lane>>4)*8+j],
// B[n=lane&15][k=(lane>>4)*8+j], D col=lane&15 row=(lane>>4)*4+reg.
// ---------------------------------------------------------------------------
template <int PASS>
__global__ __launch_bounds__(256) void gemm_split(
    const float* __restrict__ x, const short* __restrict__ wh,
    const short* __restrict__ wl, float* __restrict__ kbuf,
    float* __restrict__ dout, int* __restrict__ fixlist,
    int* __restrict__ fixcnt) {
  __shared__ char smem[65536];
  short* Bh = (short*)smem;             // 2048 chunks * 16 B = 32 KB
  short* Bl = (short*)(smem + 32768);   // 32 KB

  const int tid = threadIdx.x;
  const int lane = tid & 63;
  const int w = tid >> 6;   // wave id -> col block
  const int g = lane >> 4;  // quad 0..3
  const int n = lane & 15;
  const long r0 = (long)blockIdx.x * 64;

  f32x4 acc[4][8];
#pragma unroll
  for (int mb = 0; mb < 4; ++mb)
#pragma unroll
    for (int nb = 0; nb < 8; ++nb) acc[mb][nb] = (f32x4){0.f, 0.f, 0.f, 0.f};

  for (int kt = 0; kt < 16; ++kt) {
    // --- stage B tile (all 512 rows x 32 k, hi+lo) ---
    const uint4* srcH = (const uint4*)(wh + (long)kt * 16384);
    const uint4* srcL = (const uint4*)(wl + (long)kt * 16384);
    uint4* dstH = (uint4*)Bh;
    uint4* dstL = (uint4*)Bl;
#pragma unroll
    for (int i = 0; i < 8; ++i) {
      int c = i * 256 + tid;  // lane-sequential: coalesced load, conflict-free write
      dstH[c] = srcH[c];
      dstL[c] = srcL[c];
    }
    // --- A fragments direct from global f32 (L1-resident), split in-register ---
    short8 Ah[4], Al[4];
#pragma unroll
    for (int mb = 0; mb < 4; ++mb) {
      const float* xp = x + (r0 + mb * 16 + n) * 512 + kt * 32 + g * 8;
      float4 a0 = *(const float4*)xp;
      float4 a1 = *(const float4*)(xp + 4);
      float av[8] = {a0.x, a0.y, a0.z, a0.w, a1.x, a1.y, a1.z, a1.w};
#pragma unroll
      for (int j = 0; j < 8; ++j) {
        short h = bf16_hi(av[j]);
        Ah[mb][j] = h;
        Al[mb][j] = bf16_hi(av[j] - bf16_back(h));
      }
    }
    __syncthreads();
    // --- MFMA: 8 nb x 4 mb x 3 pairings = 96 per wave per k-iter ---
#pragma unroll
    for (int nb = 0; nb < 8; ++nb) {
      const int cb = ((w * 8 + nb) * 64 + lane) * 8;
      short8 bh = *(const short8*)(Bh + cb);
      short8 bl = *(const short8*)(Bl + cb);
#pragma unroll
      for (int mb = 0; mb < 4; ++mb) {
        acc[mb][nb] = __builtin_amdgcn_mfma_f32_16x16x32_bf16(Ah[mb], bh, acc[mb][nb], 0, 0, 0);
        acc[mb][nb] = __builtin_amdgcn_mfma_f32_16x16x32_bf16(Al[mb], bh, acc[mb][nb], 0, 0, 0);
        acc[mb][nb] = __builtin_amdgcn_mfma_f32_16x16x32_bf16(Ah[mb], bl, acc[mb][nb], 0, 0, 0);
      }
    }
    __syncthreads();
  }

  // ---------------- epilogue ----------------
  float* wss = (float*)smem;            // [4][64]
  float* wdot = (float*)(smem + 1024);  // [4][64]
  float* rowv = (float*)(smem + 2048);  // [64]

#pragma unroll
  for (int mb = 0; mb < 4; ++mb) {
#pragma unroll
    for (int reg = 0; reg < 4; ++reg) {
      const int ro = mb * 16 + g * 4 + reg;
      float ss = 0.f, dt = 0.f;
      long rprev = r0 + ro - 1;
      if (rprev < 0) rprev = 0;  // value unused for l==0 rows
#pragma unroll
      for (int nb = 0; nb < 8; ++nb) {
        float v = acc[mb][nb][reg];
        ss = fmaf(v, v, ss);
        if (PASS == 2) {
          float kp = kbuf[rprev * 512 + w * 128 + nb * 16 + n];
          dt = fmaf(v, kp, dt);
        }
      }
#pragma unroll
      for (int m = 1; m < 16; m <<= 1) {
        ss += __shfl_xor(ss, m, 64);
        if (PASS == 2) dt += __shfl_xor(dt, m, 64);
      }
      if (n == 0) {
        wss[w * 64 + ro] = ss;
        if (PASS == 2) wdot[w * 64 + ro] = dt;
      }
    }
  }
  __syncthreads();
  if (tid < 64) {
    float ss = wss[tid] + wss[64 + tid] + wss[128 + tid] + wss[192 + tid];
    float nrm = fmaxf(sqrtf(ss), 1e-12f);
    if (PASS == 1) {
      rowv[tid] = 1.0f / nrm;
    } else {
      float dt = wdot[tid] + wdot[64 + tid] + wdot[128 + tid] + wdot[192 + tid];
      const long r = r0 + tid;
      const int l = (int)(r & (LL - 1));
      float cosv = dt / nrm;
      float p;
      if (l != 0) {
        p = fminf(fmaxf(0.5f * (1.0f - cosv), 0.0f), 1.0f);
      } else {
        p = 1.0f;
      }
      dout[OUT_P + r] = p;
      dout[OUT_BHARD + r] = (p >= 0.5f) ? 1.0f : 0.0f;
      if (l != 0 && fabsf(cosv) < FIX_TAU) {
        int idx = atomicAdd(fixcnt, 1);
        if (idx < FIX_CAP) fixlist[idx] = (int)r;
      }
    }
  }
  if (PASS == 1) {
    __syncthreads();
#pragma unroll
    for (int mb = 0; mb < 4; ++mb) {
#pragma unroll
      for (int reg = 0; reg < 4; ++reg) {
        const int ro = mb * 16 + g * 4 + reg;
        const float inv = rowv[ro];
#pragma unroll
        for (int nb = 0; nb < 8; ++nb)
          kbuf[(r0 + ro) * 512 + w * 128 + nb * 16 + n] = acc[mb][nb][reg] * inv;
      }
    }
  }
}

// ---------------------------------------------------------------------------
// Pass 2b: f64 recompute of borderline rows (expected ~600 rows).
// ---------------------------------------------------------------------------
__global__ __launch_bounds__(256) void fixup(
    const float* __restrict__ x, const float* __restrict__ Wq,
    const float* __restrict__ Wk, float* __restrict__ dout,
    const int* __restrict__ fixlist, const int* __restrict__ fixcnt) {
  __shared__ float xr[512], xp[512];
  __shared__ double red[3][256];
  const int t = threadIdx.x;
  int nfix = *fixcnt;
  if (nfix > FIX_CAP) nfix = FIX_CAP;

  for (int idx = blockIdx.x; idx < nfix; idx += gridDim.x) {
    const int r = fixlist[idx];  // guaranteed l != 0
    for (int d = t; d < 512; d += 256) {
      xr[d] = x[(long)r * 512 + d];
      xp[d] = x[(long)(r - 1) * 512 + d];
    }
    __syncthreads();
    double ssq = 0.0, ssk = 0.0, dot = 0.0;
    for (int e = t; e < 512; e += 256) {
      const float* wq = Wq + (long)e * 512;
      const float* wk = Wk + (long)e * 512;
      double q = 0.0, k = 0.0;
      for (int d = 0; d < 512; ++d) {
        q = fma((double)xr[d], (double)wq[d], q);
        k = fma((double)xp[d], (double)wk[d], k);
      }
      ssq += q * q;
      ssk += k * k;
      dot += q * k;
    }
    red[0][t] = ssq;
    red[1][t] = ssk;
    red[2][t] = dot;
    __syncthreads();
    for (int s = 128; s > 0; s >>= 1) {
      if (t < s) {
        red[0][t] += red[0][t + s];
        red[1][t] += red[1][t + s];
        red[2][t] += red[2][t + s];
      }
      __syncthreads();
    }
    if (t == 0) {
      double nq = sqrt(red[0][0]);
      double nk = sqrt(red[1][0]);
      if (nq < 1e-12) nq = 1e-12;
      if (nk < 1e-12) nk = 1e-12;
      double cosd = red[2][0] / (nq * nk);
      float c = (float)cosd;
      float p = 0.5f * (1.0f - c);
      p = fminf(fmaxf(p, 0.0f), 1.0f);
      dout[OUT_P + r] = p;
      dout[OUT_BHARD + r] = (p >= 0.5f) ? 1.0f : 0.0f;
    }
    __syncthreads();
  }
}

// ---------------------------------------------------------------------------
// Pass 3: per-batch scan of b_hard -> comp_mask, p_compressed, sel, counts.
// ---------------------------------------------------------------------------
__global__ __launch_bounds__(256) void scanb(
    float* __restrict__ dout, int* __restrict__ sel,
    int* __restrict__ counts, float* __restrict__ sump) {
  __shared__ int ssum[256];
  __shared__ float spsum[256];
  __shared__ int stotal;
  const int b = blockIdx.x;
  const int t = threadIdx.x;
  const long base = (long)b * LL;

  int cnt = 0;
  float psum = 0.0f;
  for (int j = 0; j < 32; ++j) {
    int l = t * 32 + j;
    float bh = dout[OUT_BHARD + base + l];
    float pv = dout[OUT_P + base + l];
    cnt += (bh > 0.5f) ? 1 : 0;
    psum += pv;
  }
  ssum[t] = cnt;
  spsum[t] = psum;
  __syncthreads();
  if (t == 0) {
    int run = 0;
    for (int i = 0; i < 256; ++i) {
      int c = ssum[i];
      ssum[i] = run;
      run += c;
    }
    stotal = run;
  }
  __syncthreads();
  const int total = stotal;
  for (int s = 128; s > 0; s >>= 1) {
    if (t < s) spsum[t] += spsum[t + s];
    __syncthreads();
  }
  if (t == 0) {
    counts[b] = total;
    sump[b] = spsum[0];
  }
  for (int j = 0; j < 32; ++j) {
    int l = t * 32 + j;
    dout[OUT_MASK + base + l] = (l < total) ? 1.0f : 0.0f;
    dout[OUT_PCOMP + base + l] = 0.0f;
  }
  __syncthreads();
  int pos = ssum[t];
  for (int j = 0; j < 32; ++j) {
    int l = t * 32 + j;
    float bh = dout[OUT_BHARD + base + l];
    if (bh > 0.5f) {
      dout[OUT_PCOMP + base + pos] = dout[OUT_P + base + l];
      sel[base + pos] = l;
      ++pos;
    }
  }
}

// ---------------------------------------------------------------------------
// Pass 4: ratio loss.
// ---------------------------------------------------------------------------
__global__ void lossk(float* __restrict__ dout, const int* __restrict__ counts,
                      const float* __restrict__ sump) {
  if (threadIdx.x == 0 && blockIdx.x == 0) {
    float fc = 0.0f, gs = 0.0f;
    for (int b = 0; b < BB; ++b) {
      fc += (float)counts[b];
      gs += sump[b];
    }
    float F = fc / (float)NROWS;
    float G = gs / (float)NROWS;
    dout[OUT_LOSS] = 1.2f * (5.0f * F * G + (1.0f - F) * (1.0f - G));
  }
}

// ---------------------------------------------------------------------------
// Pass 5: emit compressed rows (overwrites kbuf scratch region of d_out).
// ---------------------------------------------------------------------------
__global__ __launch_bounds__(128) void emit(
    const float* __restrict__ x, float* __restrict__ dout,
    const int* __restrict__ sel, const int* __restrict__ counts) {
  const long bid = blockIdx.x;
  const int b = (int)(bid >> 13);
  const int j = (int)(bid & (LL - 1));
  const int cnt = counts[b];
  float4 v = make_float4(0.0f, 0.0f, 0.0f, 0.0f);
  if (j < cnt) {
    const int l = sel[((long)b << 13) + j];
    v = *(const float4*)(x + (((long)b << 13) + l) * 512 + threadIdx.x * 4);
  }
  *(float4*)(dout + OUT_COMP + (((long)b << 13) + j) * 512 + threadIdx.x * 4) = v;
}

// ---------------------------------------------------------------------------
extern "C" void kernel_launch(void* const* d_in, const int* in_sizes, int n_in,
                              void* d_out, int out_size, void* d_ws,
                              size_t ws_size, hipStream_t stream) {
  const float* x = (const float*)d_in[0];
  const float* Wq = (const float*)d_in[1];
  const float* Wk = (const float*)d_in[2];
  float* out = (float*)d_out;
  char* ws = (char*)d_ws;

  int* fixlist = (int*)(ws + WS_FIXLIST);
  int* fixcnt = (int*)(ws + WS_FIXCNT);
  int* counts = (int*)(ws + WS_COUNTS);
  float* sump = (float*)(ws + WS_SUMP);
  int* sel = (int*)(ws + WS_SEL);
  short* wqh = (short*)(ws + WS_WQH);
  short* wql = (short*)(ws + WS_WQL);
  short* wkh = (short*)(ws + WS_WKH);
  short* wkl = (short*)(ws + WS_WKL);

  // Stage normalized K in d_out's compressed region (134 MB); emit()
  // fully overwrites it at the end.
  float* kbuf = out + OUT_COMP;

  wsplit<<<256, 256, 0, stream>>>(Wq, Wk, wqh, wql, wkh, wkl, fixcnt);
  gemm_split<1><<<NROWS / 64, 256, 0, stream>>>(x, wkh, wkl, kbuf, out, fixlist, fixcnt);
  gemm_split<2><<<NROWS / 64, 256, 0, stream>>>(x, wqh, wql, kbuf, out, fixlist, fixcnt);
  fixup<<<512, 256, 0, stream>>>(x, Wq, Wk, out, fixlist, fixcnt);
  scanb<<<BB, 256, 0, stream>>>(out, sel, counts, sump);
  lossk<<<1, 64, 0, stream>>>(out, counts, sump);
  emit<<<NROWS, 128, 0, stream>>>(x, out, sel, counts);
}

// Round 3
// 550.257 us; speedup vs baseline: 3.8858x; 2.5174x over previous
//
#include <hip/hip_runtime.h>
#include <hip/hip_bf16.h>
#include <math.h>

// Problem constants
#define BB 8
#define LL 8192
#define DD 512
#define NROWS (BB * LL)  // 65536

// d_out layout (floats)
#define OUT_COMP   0
#define OUT_MASK   33554432
#define OUT_BHARD  33619968
#define OUT_P      33685504
#define OUT_PCOMP  33751040
#define OUT_LOSS   33816576

// ws layout (bytes)
#define WS_FIXLIST 0         // 65536*4
#define WS_FIXCNT  262144    // 4
#define WS_COUNTS  262148    // 32
#define WS_SUMP    262180    // 32
#define WS_SEL     262212    // 65536*4 -> 524356
#define WS_SSK     524416    // 65536*4
#define WS_SSQ     786560    // 65536*4
#define WS_DOT     1048704   // 65536*4
#define WS_WQH     1310848   // 512 KB each
#define WS_WQL     1835136
#define WS_WKH     2359424
#define WS_WKL     2883712   // end 3408000 (~3.4 MB)

#define FIX_CAP 65536
#define FIX_TAU 2e-4f

typedef __attribute__((ext_vector_type(8))) short short8;
typedef __attribute__((ext_vector_type(4))) float f32x4;

static __device__ __forceinline__ short bf16_hi(float x) {
  __hip_bfloat16 h = __float2bfloat16(x);
  return __builtin_bit_cast(short, h);
}
static __device__ __forceinline__ float bf16_back(short s) {
  __hip_bfloat16 h = __builtin_bit_cast(__hip_bfloat16, s);
  return __bfloat162float(h);
}

// async global->LDS, 16 B per lane; lds base must be wave-uniform, data lands
// at lds + lane*16 (m104/m108 caveat) -- our layouts are lane-sequential.
static __device__ __forceinline__ void ld_g2l16(const void* g, void* l) {
  __builtin_amdgcn_global_load_lds(
      (const __attribute__((address_space(1))) void*)g,
      (__attribute__((address_space(3))) void*)l, 16, 0, 0);
}

// ---------------------------------------------------------------------------
// Pass 0: split Wq,Wk into bf16 hi/lo, fragment-chunk order:
// chunk c = (kt*32 + ct)*64 + l, l = kblk*16 + n; holds W[e=ct*16+n][d=kt*32+kblk*8 ..+8].
// Also zero-inits the ss/dot accumulators and fixcnt.
// ---------------------------------------------------------------------------
__global__ __launch_bounds__(256) void wsplit(
    const float* __restrict__ Wq, const float* __restrict__ Wk,
    short* __restrict__ wqh, short* __restrict__ wql,
    short* __restrict__ wkh, short* __restrict__ wkl,
    float* __restrict__ ssk, float* __restrict__ ssq,
    float* __restrict__ dotb, int* __restrict__ fixcnt) {
  const int t = blockIdx.x * 256 + threadIdx.x;  // 0..65535
  if (t == 0) *fixcnt = 0;
  ssk[t] = 0.0f;
  ssq[t] = 0.0f;
  dotb[t] = 0.0f;

  const int m = t >> 15;         // 0 = Wq, 1 = Wk
  const int c = t & 32767;       // chunk id
  const int kt = c >> 11;
  const int ct = (c >> 6) & 31;
  const int l = c & 63;
  const int n = l & 15;
  const int kblk = l >> 4;
  const int e = ct * 16 + n;
  const int d0 = kt * 32 + kblk * 8;
  const float* src = (m ? Wk : Wq) + (long)e * 512 + d0;
  short* dh = (m ? wkh : wqh) + (long)c * 8;
  short* dl = (m ? wkl : wql) + (long)c * 8;
  float4 v0 = *(const float4*)src;
  float4 v1 = *(const float4*)(src + 4);
  float av[8] = {v0.x, v0.y, v0.z, v0.w, v1.x, v1.y, v1.z, v1.w};
  short8 hi, lo;
#pragma unroll
  for (int j = 0; j < 8; ++j) {
    short hh = bf16_hi(av[j]);
    hi[j] = hh;
    lo[j] = bf16_hi(av[j] - bf16_back(hh));
  }
  *(short8*)dh = hi;
  *(short8*)dl = lo;
}

// ---------------------------------------------------------------------------
// GEMM: C = x * W^T, 128x128 tile, BK=32, 4 waves in 2x2 (wave w: rows
// (w&1)*64, cols (w>>1)*64), acc 4x4 16x16 tiles. Split-bf16 3 pairings.
// PASS 1: store raw C to kbuf, atomicAdd row ss -> ssk.
// PASS 2: read kbuf[r-1], atomicAdd row ss -> ssq, row dot -> dotb.
// ---------------------------------------------------------------------------
template <int PASS>
__global__ __launch_bounds__(256, 2) void gemm_tile(
    const float* __restrict__ x, const short* __restrict__ wh,
    const short* __restrict__ wl, float* __restrict__ kbuf,
    float* __restrict__ ssOut, float* __restrict__ dotOut) {
  __shared__ uint4 smem4[2048];  // 32 KB
  short* AH = (short*)smem4;     // 4096 shorts (8 KB): chunk (mb*64+lane)*8
  short* AL = AH + 4096;
  short* BH = AL + 4096;         // chunk ((wcol*4+nb)*64+lane)*8
  short* BL = BH + 4096;

  const int tid = threadIdx.x;
  const int lane = tid & 63;
  const int w = tid >> 6;
  const int wrow = w & 1, wcol = w >> 1;
  const int g = lane >> 4, n = lane & 15;
  const int bx = blockIdx.x;
  const int rb = bx >> 2, cb = bx & 3;
  const long r0 = (long)rb * 128;

  // A staging role: thread -> (row m128, k-half h)
  const int m128 = tid >> 1, h = tid & 1;
  const int mbs = m128 >> 4, ms = m128 & 15;
  const float* xrow = x + (r0 + m128) * 512 + h * 16;
  short* paH = AH + ((mbs * 4 + 2 * h) * 16 + ms) * 8;
  short* paL = AL + ((mbs * 4 + 2 * h) * 16 + ms) * 8;

  f32x4 acc[4][4];
#pragma unroll
  for (int mb = 0; mb < 4; ++mb)
#pragma unroll
    for (int nb = 0; nb < 4; ++nb) acc[mb][nb] = (f32x4){0.f, 0.f, 0.f, 0.f};

  // prefetch A regs for kt=0
  float4 f0 = *(const float4*)(xrow + 0);
  float4 f1 = *(const float4*)(xrow + 4);
  float4 f2 = *(const float4*)(xrow + 8);
  float4 f3 = *(const float4*)(xrow + 12);

  for (int kt = 0; kt < 16; ++kt) {
    // --- B tile async: 8 KB hi + 8 KB lo, wave w stages its 2 KB quarter ---
    const long bbase = ((long)(kt * 32 + cb * 8) << 9) + w * 1024 + lane * 8;
    ld_g2l16(wh + bbase, BH + w * 1024);
    ld_g2l16(wh + bbase + 512, BH + w * 1024 + 512);
    ld_g2l16(wl + bbase, BL + w * 1024);
    ld_g2l16(wl + bbase + 512, BL + w * 1024 + 512);
    // --- A: convert prefetched f32 regs -> bf16 hi/lo chunks in LDS ---
    {
      float av[16] = {f0.x, f0.y, f0.z, f0.w, f1.x, f1.y, f1.z, f1.w,
                      f2.x, f2.y, f2.z, f2.w, f3.x, f3.y, f3.z, f3.w};
      short8 h0, h1, l0, l1;
#pragma unroll
      for (int j = 0; j < 8; ++j) {
        short a = bf16_hi(av[j]);
        h0[j] = a;
        l0[j] = bf16_hi(av[j] - bf16_back(a));
        short b = bf16_hi(av[8 + j]);
        h1[j] = b;
        l1[j] = bf16_hi(av[8 + j] - bf16_back(b));
      }
      *(short8*)paH = h0;
      *(short8*)(paH + 128) = h1;  // next kblk chunk: +16 chunks * 8 shorts
      *(short8*)paL = l0;
      *(short8*)(paL + 128) = l1;
    }
    __syncthreads();
    if (kt < 15) {
      const float* xp = xrow + (kt + 1) * 32;
      f0 = *(const float4*)(xp + 0);
      f1 = *(const float4*)(xp + 4);
      f2 = *(const float4*)(xp + 8);
      f3 = *(const float4*)(xp + 12);
    }
    // --- fragments + MFMA ---
    short8 ah[4], al[4], bh[4], bl[4];
#pragma unroll
    for (int mb = 0; mb < 4; ++mb) {
      const int ar = (((wrow * 4 + mb) & 3) * 64 + lane) * 8;  // wrow selects row half via mb offset below
      ah[mb] = *(const short8*)(AH + ((wrow * 4 + mb) * 64 % 4096) + 0 * 0 + ar * 0);  // placeholder
      (void)ar;
    }
    // NOTE: A tile holds all 128 rows (8 mb-chunks of 16 rows); wave's rows are
    // wrow*64 + mb*16, i.e. chunk index cm = wrow*4 + mb... but AH is laid out
    // with mb in [0,8): chunk (cm*64 + lane). Recompute properly:
#pragma unroll
    for (int mb = 0; mb < 4; ++mb) {
      const int cm = wrow * 4 + mb;  // 0..7 -- wait, staging used mbs in [0,8)
      ah[mb] = *(const short8*)(AH + (cm * 64 + lane) * 8 % 4096);
      al[mb] = *(const short8*)(AL + (cm * 64 + lane) * 8 % 4096);
    }
#pragma unroll
    for (int nb = 0; nb < 4; ++nb) {
      bh[nb] = *(const short8*)(BH + ((wcol * 4 + nb) * 64 + lane) * 8);
      bl[nb] = *(const short8*)(BL + ((wcol * 4 + nb) * 64 + lane) * 8);
    }
#pragma unroll
    for (int nb = 0; nb < 4; ++nb)
#pragma unroll
      for (int mb = 0; mb < 4; ++mb) {
        acc[mb][nb] = __builtin_amdgcn_mfma_f32_16x16x32_bf16(ah[mb], bh[nb], acc[mb][nb], 0, 0, 0);
        acc[mb][nb] = __builtin_amdgcn_mfma_f32_16x16x32_bf16(al[mb], bh[nb], acc[mb][nb], 0, 0, 0);
        acc[mb][nb] = __builtin_amdgcn_mfma_f32_16x16x32_bf16(ah[mb], bl[nb], acc[mb][nb], 0, 0, 0);
      }
    __syncthreads();
  }

  // ---------------- epilogue: raw C + row partials ----------------
  const int colbase = cb * 128 + wcol * 64 + n;
#pragma unroll
  for (int mb = 0; mb < 4; ++mb) {
#pragma unroll
    for (int reg = 0; reg < 4; ++reg) {
      const long row = r0 + wrow * 64 + mb * 16 + g * 4 + reg;
      float ss = 0.f, dt = 0.f;
      const long rp = (row > 0) ? row - 1 : 0;
#pragma unroll
      for (int nb = 0; nb < 4; ++nb) {
        float v = acc[mb][nb][reg];
        ss = fmaf(v, v, ss);
        if (PASS == 1) {
          kbuf[row * 512 + colbase + nb * 16] = v;
        } else {
          float kp = kbuf[rp * 512 + colbase + nb * 16];
          dt = fmaf(v, kp, dt);
        }
      }
#pragma unroll
      for (int m = 1; m < 16; m <<= 1) {
        ss += __shfl_xor(ss, m, 64);
        if (PASS == 2) dt += __shfl_xor(dt, m, 64);
      }
      if (n == 0) {
        atomicAdd(&ssOut[row], ss);
        if (PASS == 2) atomicAdd(&dotOut[row], dt);
      }
    }
  }
}

// ---------------------------------------------------------------------------
// Combine: cos from partials -> p, b_hard, fixlist.
// ---------------------------------------------------------------------------
__global__ __launch_bounds__(256) void combine(
    const float* __restrict__ ssq, const float* __restrict__ ssk,
    const float* __restrict__ dotb, float* __restrict__ dout,
    int* __restrict__ fixlist, int* __restrict__ fixcnt) {
  const int r = blockIdx.x * 256 + threadIdx.x;
  const int l = r & (LL - 1);
  float p;
  float cosv = 0.0f;
  if (l != 0) {
    float nq = fmaxf(sqrtf(ssq[r]), 1e-12f);
    float nk = fmaxf(sqrtf(ssk[r - 1]), 1e-12f);
    cosv = dotb[r] / (nq * nk);
    p = fminf(fmaxf(0.5f * (1.0f - cosv), 0.0f), 1.0f);
  } else {
    p = 1.0f;
  }
  dout[OUT_P + r] = p;
  dout[OUT_BHARD + r] = (p >= 0.5f) ? 1.0f : 0.0f;
  if (l != 0 && fabsf(cosv) < FIX_TAU) {
    int idx = atomicAdd(fixcnt, 1);
    if (idx < FIX_CAP) fixlist[idx] = r;
  }
}

// ---------------------------------------------------------------------------
// f64 recompute of borderline rows (expected ~250 rows).
// ---------------------------------------------------------------------------
__global__ __launch_bounds__(256) void fixup(
    const float* __restrict__ x, const float* __restrict__ Wq,
    const float* __restrict__ Wk, float* __restrict__ dout,
    const int* __restrict__ fixlist, const int* __restrict__ fixcnt) {
  __shared__ float xr[512], xp[512];
  __shared__ double red[3][256];
  const int t = threadIdx.x;
  int nfix = *fixcnt;
  if (nfix > FIX_CAP) nfix = FIX_CAP;

  for (int idx = blockIdx.x; idx < nfix; idx += gridDim.x) {
    const int r = fixlist[idx];
    for (int d = t; d < 512; d += 256) {
      xr[d] = x[(long)r * 512 + d];
      xp[d] = x[(long)(r - 1) * 512 + d];
    }
    __syncthreads();
    double ssq = 0.0, ssk = 0.0, dot = 0.0;
    for (int e = t; e < 512; e += 256) {
      const float* wq = Wq + (long)e * 512;
      const float* wk = Wk + (long)e * 512;
      double q = 0.0, k = 0.0;
      for (int d = 0; d < 512; ++d) {
        q = fma((double)xr[d], (double)wq[d], q);
        k = fma((double)xp[d], (double)wk[d], k);
      }
      ssq += q * q;
      ssk += k * k;
      dot += q * k;
    }
    red[0][t] = ssq;
    red[1][t] = ssk;
    red[2][t] = dot;
    __syncthreads();
    for (int s = 128; s > 0; s >>= 1) {
      if (t < s) {
        red[0][t] += red[0][t + s];
        red[1][t] += red[1][t + s];
        red[2][t] += red[2][t + s];
      }
      __syncthreads();
    }
    if (t == 0) {
      double nq = sqrt(red[0][0]);
      double nk = sqrt(red[1][0]);
      if (nq < 1e-12) nq = 1e-12;
      if (nk < 1e-12) nk = 1e-12;
      float c = (float)(red[2][0] / (nq * nk));
      float p = fminf(fmaxf(0.5f * (1.0f - c), 0.0f), 1.0f);
      dout[OUT_P + r] = p;
      dout[OUT_BHARD + r] = (p >= 0.5f) ? 1.0f : 0.0f;
    }
    __syncthreads();
  }
}

// ---------------------------------------------------------------------------
// Per-batch scan (shfl-based), mask, p_compressed, sel, counts.
// ---------------------------------------------------------------------------
__global__ __launch_bounds__(256) void scanb(
    float* __restrict__ dout, int* __restrict__ sel,
    int* __restrict__ counts, float* __restrict__ sump) {
  __shared__ int wtot[4];
  __shared__ float wps[4];
  const int b = blockIdx.x;
  const int t = threadIdx.x;
  const int lane = t & 63, wv = t >> 6;
  const long base = (long)b * LL;

  int cnt = 0;
  float psum = 0.0f;
#pragma unroll 4
  for (int j = 0; j < 32; ++j) {
    int l = t * 32 + j;
    float bh = dout[OUT_BHARD + base + l];
    float pv = dout[OUT_P + base + l];
    cnt += (bh > 0.5f) ? 1 : 0;
    psum += pv;
  }
  // wave inclusive scan of cnt
  int inc = cnt;
#pragma unroll
  for (int off = 1; off < 64; off <<= 1) {
    int u = __shfl_up(inc, off, 64);
    if (lane >= off) inc += u;
  }
  float ps = psum;
#pragma unroll
  for (int off = 1; off < 64; off <<= 1) ps += __shfl_xor(ps, off, 64);
  if (lane == 63) wtot[wv] = inc;
  if (lane == 0) wps[wv] = ps;
  __syncthreads();
  int wbase = 0, total = 0;
#pragma unroll
  for (int i = 0; i < 4; ++i) {
    int c = wtot[i];
    if (i < wv) wbase += c;
    total += c;
  }
  if (t == 0) {
    counts[b] = total;
    sump[b] = wps[0] + wps[1] + wps[2] + wps[3];
  }
  for (int j = 0; j < 32; ++j) {
    int l = t * 32 + j;
    dout[OUT_MASK + base + l] = (l < total) ? 1.0f : 0.0f;
    dout[OUT_PCOMP + base + l] = 0.0f;
  }
  __syncthreads();
  int pos = wbase + inc - cnt;  // exclusive prefix
  for (int j = 0; j < 32; ++j) {
    int l = t * 32 + j;
    float bh = dout[OUT_BHARD + base + l];
    if (bh > 0.5f) {
      dout[OUT_PCOMP + base + pos] = dout[OUT_P + base + l];
      sel[base + pos] = l;
      ++pos;
    }
  }
}

// ---------------------------------------------------------------------------
__global__ void lossk(float* __restrict__ dout, const int* __restrict__ counts,
                      const float* __restrict__ sump) {
  if (threadIdx.x == 0 && blockIdx.x == 0) {
    float fc = 0.0f, gs = 0.0f;
    for (int b = 0; b < BB; ++b) {
      fc += (float)counts[b];
      gs += sump[b];
    }
    float F = fc / (float)NROWS;
    float G = gs / (float)NROWS;
    dout[OUT_LOSS] = 1.2f * (5.0f * F * G + (1.0f - F) * (1.0f - G));
  }
}

// ---------------------------------------------------------------------------
__global__ __launch_bounds__(128) void emit(
    const float* __restrict__ x, float* __restrict__ dout,
    const int* __restrict__ sel, const int* __restrict__ counts) {
  const long bid = blockIdx.x;
  const int b = (int)(bid >> 13);
  const int j = (int)(bid & (LL - 1));
  const int cnt = counts[b];
  float4 v = make_float4(0.0f, 0.0f, 0.0f, 0.0f);
  if (j < cnt) {
    const int l = sel[((long)b << 13) + j];
    v = *(const float4*)(x + (((long)b << 13) + l) * 512 + threadIdx.x * 4);
  }
  *(float4*)(dout + OUT_COMP + (((long)b << 13) + j) * 512 + threadIdx.x * 4) = v;
}

// ---------------------------------------------------------------------------
extern "C" void kernel_launch(void* const* d_in, const int* in_sizes, int n_in,
                              void* d_out, int out_size, void* d_ws,
                              size_t ws_size, hipStream_t stream) {
  const float* x = (const float*)d_in[0];
  const float* Wq = (const float*)d_in[1];
  const float* Wk = (const float*)d_in[2];
  float* out = (float*)d_out;
  char* ws = (char*)d_ws;

  int* fixlist = (int*)(ws + WS_FIXLIST);
  int* fixcnt = (int*)(ws + WS_FIXCNT);
  int* counts = (int*)(ws + WS_COUNTS);
  float* sump = (float*)(ws + WS_SUMP);
  int* sel = (int*)(ws + WS_SEL);
  float* ssk = (float*)(ws + WS_SSK);
  float* ssq = (float*)(ws + WS_SSQ);
  float* dotb = (float*)(ws + WS_DOT);
  short* wqh = (short*)(ws + WS_WQH);
  short* wql = (short*)(ws + WS_WQL);
  short* wkh = (short*)(ws + WS_WKH);
  short* wkl = (short*)(ws + WS_WKL);

  float* kbuf = out + OUT_COMP;  // raw k; overwritten by emit at the end

  wsplit<<<256, 256, 0, stream>>>(Wq, Wk, wqh, wql, wkh, wkl, ssk, ssq, dotb, fixcnt);
  gemm_tile<1><<<2048, 256, 0, stream>>>(x, wkh, wkl, kbuf, ssk, nullptr);
  gemm_tile<2><<<2048, 256, 0, stream>>>(x, wqh, wql, kbuf, ssq, dotb);
  combine<<<NROWS / 256, 256, 0, stream>>>(ssq, ssk, dotb, out, fixlist, fixcnt);
  fixup<<<512, 256, 0, stream>>>(x, Wq, Wk, out, fixlist, fixcnt);
  scanb<<<BB, 256, 0, stream>>>(out, sel, counts, sump);
  lossk<<<1, 64, 0, stream>>>(out, counts, sump);
  emit<<<NROWS, 128, 0, stream>>>(x, out, sel, counts);
}

// Round 4
// 545.013 us; speedup vs baseline: 3.9232x; 1.0096x over previous
//
#include <hip/hip_runtime.h>
#include <hip/hip_bf16.h>
#include <math.h>

// Problem constants
#define BB 8
#define LL 8192
#define DD 512
#define NROWS (BB * LL)  // 65536

// d_out layout (floats)
#define OUT_COMP   0
#define OUT_MASK   33554432
#define OUT_BHARD  33619968
#define OUT_P      33685504
#define OUT_PCOMP  33751040
#define OUT_LOSS   33816576

// ws layout (bytes)
#define WS_FIXLIST 0         // 65536*4
#define WS_FIXCNT  262144    // 4
#define WS_COUNTS  262148    // 32
#define WS_SUMP    262180    // 32
#define WS_SEL     262212    // 65536*4 -> 524356
#define WS_SSK     524416    // 65536*4
#define WS_SSQ     786560    // 65536*4
#define WS_DOT     1048704   // 65536*4
#define WS_WQH     1310848   // 512 KB each
#define WS_WQL     1835136
#define WS_WKH     2359424
#define WS_WKL     2883712   // end ~3.4 MB

#define FIX_CAP 65536
#define FIX_TAU 1e-4f

typedef __attribute__((ext_vector_type(8))) _Float16 half8;
typedef __attribute__((ext_vector_type(4))) float f32x4;

// async global->LDS, 16 B per lane; lds base wave-uniform, data lands at
// lds + lane*16 (m104/m108) -- layouts below are lane-sequential.
static __device__ __forceinline__ void ld_g2l16(const void* g, void* l) {
  __builtin_amdgcn_global_load_lds(
      (const __attribute__((address_space(1))) void*)g,
      (__attribute__((address_space(3))) void*)l, 16, 0, 0);
}

// ---------------------------------------------------------------------------
// Pass 0: split Wq,Wk into f16 hi/lo (hi = f16(w), lo = f16(w - hi)),
// fragment-chunk order: chunk c = (kt*32 + ct)*64 + kblk*16 + n holds
// W[e = ct*16+n][d = kt*32 + kblk*8 .. +8]. Also zero-inits accumulators.
// ---------------------------------------------------------------------------
__global__ __launch_bounds__(256) void wsplit(
    const float* __restrict__ Wq, const float* __restrict__ Wk,
    _Float16* __restrict__ wqh, _Float16* __restrict__ wql,
    _Float16* __restrict__ wkh, _Float16* __restrict__ wkl,
    float* __restrict__ ssk, float* __restrict__ ssq,
    float* __restrict__ dotb, int* __restrict__ fixcnt) {
  const int t = blockIdx.x * 256 + threadIdx.x;  // 0..65535
  if (t == 0) *fixcnt = 0;
  ssk[t] = 0.0f;
  ssq[t] = 0.0f;
  dotb[t] = 0.0f;

  const int m = t >> 15;         // 0 = Wq, 1 = Wk
  const int c = t & 32767;       // chunk id
  const int kt = c >> 11;
  const int ct = (c >> 6) & 31;
  const int l = c & 63;
  const int n = l & 15;
  const int kblk = l >> 4;
  const int e = ct * 16 + n;
  const int d0 = kt * 32 + kblk * 8;
  const float* src = (m ? Wk : Wq) + (long)e * 512 + d0;
  _Float16* dh = (m ? wkh : wqh) + (long)c * 8;
  _Float16* dl = (m ? wkl : wql) + (long)c * 8;
  float4 v0 = *(const float4*)src;
  float4 v1 = *(const float4*)(src + 4);
  float av[8] = {v0.x, v0.y, v0.z, v0.w, v1.x, v1.y, v1.z, v1.w};
  half8 hi, lo;
#pragma unroll
  for (int j = 0; j < 8; ++j) {
    _Float16 hh = (_Float16)av[j];
    hi[j] = hh;
    lo[j] = (_Float16)(av[j] - (float)hh);
  }
  *(half8*)dh = hi;
  *(half8*)dl = lo;
}

// ---------------------------------------------------------------------------
// GEMM: C = x * W^T, 128x128 tile, BK=32, 4 waves 2x2. f16 split, 3 pairings
// (hi*hi + lo*hi + hi*lo; residual ~1e-5 in cos, covered by f64 fixup).
// A staging: thread tid stages chunks tid and tid+256 -> ds_write_b128 is
// lane-sequential (conflict-free; round-3 map cost 4.19M conflict cycles).
// PASS 1: store raw C as f16 -> kbuf, atomicAdd row ss -> ssk.
// PASS 2: read kbuf[r-1], atomicAdd row ss -> ssq, row dot -> dotb.
// ---------------------------------------------------------------------------
template <int PASS>
__global__ __launch_bounds__(256, 2) void gemm_tile(
    const float* __restrict__ x, const _Float16* __restrict__ wh,
    const _Float16* __restrict__ wl, _Float16* __restrict__ kbuf,
    float* __restrict__ ssOut, float* __restrict__ dotOut) {
  __shared__ _Float16 smem[16384];  // 32 KB
  _Float16* AH = smem;              // chunks 0..511: (mbs*64 + kblk*16 + ms)
  _Float16* AL = AH + 4096;
  _Float16* BH = AL + 4096;         // chunks: (ctl*64 + kblk*16 + n)
  _Float16* BL = BH + 4096;

  const int tid = threadIdx.x;
  const int lane = tid & 63;
  const int w = tid >> 6;
  const int wrow = w & 1, wcol = w >> 1;
  const int g = lane >> 4, n = lane & 15;
  const int bx = blockIdx.x;
  const int rb = bx >> 2, cb = bx & 3;
  const long r0 = (long)rb * 128;

  // A staging: tid = (mbs<<6)|(kblk<<4)|ms -> chunk c1=tid (row arow),
  // chunk c2=tid+256 (row arow+64). 8 consecutive floats at col akb*8.
  const int arow = ((tid >> 6) << 4) | (tid & 15);
  const int akb = (tid >> 4) & 3;
  const float* ap = x + (r0 + arow) * 512 + akb * 8;

  f32x4 acc[4][4];
#pragma unroll
  for (int mb = 0; mb < 4; ++mb)
#pragma unroll
    for (int nb = 0; nb < 4; ++nb) acc[mb][nb] = (f32x4){0.f, 0.f, 0.f, 0.f};

  // prefetch A for kt=0
  float4 f0 = *(const float4*)(ap);
  float4 f1 = *(const float4*)(ap + 4);
  float4 f2 = *(const float4*)(ap + 64 * 512);
  float4 f3 = *(const float4*)(ap + 64 * 512 + 4);

  for (int kt = 0; kt < 16; ++kt) {
    // --- B tile async: 8 KB hi + 8 KB lo; wave w stages 2 KB of each ---
    const long bbase = ((long)(kt * 32 + cb * 8) << 9) + w * 1024 + lane * 8;
    ld_g2l16(wh + bbase, BH + w * 1024);
    ld_g2l16(wh + bbase + 512, BH + w * 1024 + 512);
    ld_g2l16(wl + bbase, BL + w * 1024);
    ld_g2l16(wl + bbase + 512, BL + w * 1024 + 512);
    // --- A: f32 regs -> f16 hi/lo chunks, lane-sequential writes ---
    {
      float av0[8] = {f0.x, f0.y, f0.z, f0.w, f1.x, f1.y, f1.z, f1.w};
      float av1[8] = {f2.x, f2.y, f2.z, f2.w, f3.x, f3.y, f3.z, f3.w};
      half8 h0, h1, l0, l1;
#pragma unroll
      for (int j = 0; j < 8; ++j) {
        _Float16 a = (_Float16)av0[j];
        h0[j] = a;
        l0[j] = (_Float16)(av0[j] - (float)a);
        _Float16 b = (_Float16)av1[j];
        h1[j] = b;
        l1[j] = (_Float16)(av1[j] - (float)b);
      }
      *(half8*)(AH + tid * 8) = h0;
      *(half8*)(AH + (tid + 256) * 8) = h1;
      *(half8*)(AL + tid * 8) = l0;
      *(half8*)(AL + (tid + 256) * 8) = l1;
    }
    __syncthreads();
    if (kt < 15) {
      const float* xp = ap + (kt + 1) * 32;
      f0 = *(const float4*)(xp);
      f1 = *(const float4*)(xp + 4);
      f2 = *(const float4*)(xp + 64 * 512);
      f3 = *(const float4*)(xp + 64 * 512 + 4);
    }
    // --- fragments + MFMA ---
    half8 ah[4], al[4], bh[4], bl[4];
#pragma unroll
    for (int mb = 0; mb < 4; ++mb) {
      const int cm = wrow * 4 + mb;
      ah[mb] = *(const half8*)(AH + (cm * 64 + lane) * 8);
      al[mb] = *(const half8*)(AL + (cm * 64 + lane) * 8);
    }
#pragma unroll
    for (int nb = 0; nb < 4; ++nb) {
      bh[nb] = *(const half8*)(BH + ((wcol * 4 + nb) * 64 + lane) * 8);
      bl[nb] = *(const half8*)(BL + ((wcol * 4 + nb) * 64 + lane) * 8);
    }
#pragma unroll
    for (int nb = 0; nb < 4; ++nb)
#pragma unroll
      for (int mb = 0; mb < 4; ++mb) {
        acc[mb][nb] = __builtin_amdgcn_mfma_f32_16x16x32_f16(ah[mb], bh[nb], acc[mb][nb], 0, 0, 0);
        acc[mb][nb] = __builtin_amdgcn_mfma_f32_16x16x32_f16(al[mb], bh[nb], acc[mb][nb], 0, 0, 0);
        acc[mb][nb] = __builtin_amdgcn_mfma_f32_16x16x32_f16(ah[mb], bl[nb], acc[mb][nb], 0, 0, 0);
      }
    __syncthreads();
  }

  // ---------------- epilogue: raw C (f16) + row partials ----------------
  const int colbase = cb * 128 + wcol * 64 + n;
#pragma unroll
  for (int mb = 0; mb < 4; ++mb) {
#pragma unroll
    for (int reg = 0; reg < 4; ++reg) {
      const long row = r0 + wrow * 64 + mb * 16 + g * 4 + reg;
      float ss = 0.f, dt = 0.f;
      const long rp = (row > 0) ? row - 1 : 0;
#pragma unroll
      for (int nb = 0; nb < 4; ++nb) {
        float v = acc[mb][nb][reg];
        ss = fmaf(v, v, ss);
        if (PASS == 1) {
          kbuf[row * 512 + colbase + nb * 16] = (_Float16)v;
        } else {
          float kp = (float)kbuf[rp * 512 + colbase + nb * 16];
          dt = fmaf(v, kp, dt);
        }
      }
#pragma unroll
      for (int m = 1; m < 16; m <<= 1) {
        ss += __shfl_xor(ss, m, 64);
        if (PASS == 2) dt += __shfl_xor(dt, m, 64);
      }
      if (n == 0) {
        atomicAdd(&ssOut[row], ss);
        if (PASS == 2) atomicAdd(&dotOut[row], dt);
      }
    }
  }
}

// ---------------------------------------------------------------------------
// Combine: cos from partials -> p, b_hard, fixlist.
// ---------------------------------------------------------------------------
__global__ __launch_bounds__(256) void combine(
    const float* __restrict__ ssq, const float* __restrict__ ssk,
    const float* __restrict__ dotb, float* __restrict__ dout,
    int* __restrict__ fixlist, int* __restrict__ fixcnt) {
  const int r = blockIdx.x * 256 + threadIdx.x;
  const int l = r & (LL - 1);
  float p;
  float cosv = 0.0f;
  if (l != 0) {
    float nq = fmaxf(sqrtf(ssq[r]), 1e-12f);
    float nk = fmaxf(sqrtf(ssk[r - 1]), 1e-12f);
    cosv = dotb[r] / (nq * nk);
    p = fminf(fmaxf(0.5f * (1.0f - cosv), 0.0f), 1.0f);
  } else {
    p = 1.0f;
  }
  dout[OUT_P + r] = p;
  dout[OUT_BHARD + r] = (p >= 0.5f) ? 1.0f : 0.0f;
  if (l != 0 && fabsf(cosv) < FIX_TAU) {
    int idx = atomicAdd(fixcnt, 1);
    if (idx < FIX_CAP) fixlist[idx] = r;
  }
}

// ---------------------------------------------------------------------------
// f64 recompute of borderline rows (expected ~120 rows at TAU=1e-4).
// ---------------------------------------------------------------------------
__global__ __launch_bounds__(256) void fixup(
    const float* __restrict__ x, const float* __restrict__ Wq,
    const float* __restrict__ Wk, float* __restrict__ dout,
    const int* __restrict__ fixlist, const int* __restrict__ fixcnt) {
  __shared__ float xr[512], xp[512];
  __shared__ double red[3][256];
  const int t = threadIdx.x;
  int nfix = *fixcnt;
  if (nfix > FIX_CAP) nfix = FIX_CAP;

  for (int idx = blockIdx.x; idx < nfix; idx += gridDim.x) {
    const int r = fixlist[idx];
    for (int d = t; d < 512; d += 256) {
      xr[d] = x[(long)r * 512 + d];
      xp[d] = x[(long)(r - 1) * 512 + d];
    }
    __syncthreads();
    double ssq = 0.0, ssk = 0.0, dot = 0.0;
    for (int e = t; e < 512; e += 256) {
      const float* wq = Wq + (long)e * 512;
      const float* wk = Wk + (long)e * 512;
      double q = 0.0, k = 0.0;
      for (int d = 0; d < 512; ++d) {
        q = fma((double)xr[d], (double)wq[d], q);
        k = fma((double)xp[d], (double)wk[d], k);
      }
      ssq += q * q;
      ssk += k * k;
      dot += q * k;
    }
    red[0][t] = ssq;
    red[1][t] = ssk;
    red[2][t] = dot;
    __syncthreads();
    for (int s = 128; s > 0; s >>= 1) {
      if (t < s) {
        red[0][t] += red[0][t + s];
        red[1][t] += red[1][t + s];
        red[2][t] += red[2][t + s];
      }
      __syncthreads();
    }
    if (t == 0) {
      double nq = sqrt(red[0][0]);
      double nk = sqrt(red[1][0]);
      if (nq < 1e-12) nq = 1e-12;
      if (nk < 1e-12) nk = 1e-12;
      float c = (float)(red[2][0] / (nq * nk));
      float p = fminf(fmaxf(0.5f * (1.0f - c), 0.0f), 1.0f);
      dout[OUT_P + r] = p;
      dout[OUT_BHARD + r] = (p >= 0.5f) ? 1.0f : 0.0f;
    }
    __syncthreads();
  }
}

// ---------------------------------------------------------------------------
// Per-batch scan (shfl-based), mask, p_compressed, sel, counts.
// ---------------------------------------------------------------------------
__global__ __launch_bounds__(256) void scanb(
    float* __restrict__ dout, int* __restrict__ sel,
    int* __restrict__ counts, float* __restrict__ sump) {
  __shared__ int wtot[4];
  __shared__ float wps[4];
  const int b = blockIdx.x;
  const int t = threadIdx.x;
  const int lane = t & 63, wv = t >> 6;
  const long base = (long)b * LL;

  int cnt = 0;
  float psum = 0.0f;
#pragma unroll 4
  for (int j = 0; j < 32; ++j) {
    int l = t * 32 + j;
    float bh = dout[OUT_BHARD + base + l];
    float pv = dout[OUT_P + base + l];
    cnt += (bh > 0.5f) ? 1 : 0;
    psum += pv;
  }
  int inc = cnt;
#pragma unroll
  for (int off = 1; off < 64; off <<= 1) {
    int u = __shfl_up(inc, off, 64);
    if (lane >= off) inc += u;
  }
  float ps = psum;
#pragma unroll
  for (int off = 1; off < 64; off <<= 1) ps += __shfl_xor(ps, off, 64);
  if (lane == 63) wtot[wv] = inc;
  if (lane == 0) wps[wv] = ps;
  __syncthreads();
  int wbase = 0, total = 0;
#pragma unroll
  for (int i = 0; i < 4; ++i) {
    int c = wtot[i];
    if (i < wv) wbase += c;
    total += c;
  }
  if (t == 0) {
    counts[b] = total;
    sump[b] = wps[0] + wps[1] + wps[2] + wps[3];
  }
  for (int j = 0; j < 32; ++j) {
    int l = t * 32 + j;
    dout[OUT_MASK + base + l] = (l < total) ? 1.0f : 0.0f;
    dout[OUT_PCOMP + base + l] = 0.0f;
  }
  __syncthreads();
  int pos = wbase + inc - cnt;  // exclusive prefix
  for (int j = 0; j < 32; ++j) {
    int l = t * 32 + j;
    float bh = dout[OUT_BHARD + base + l];
    if (bh > 0.5f) {
      dout[OUT_PCOMP + base + pos] = dout[OUT_P + base + l];
      sel[base + pos] = l;
      ++pos;
    }
  }
}

// ---------------------------------------------------------------------------
__global__ void lossk(float* __restrict__ dout, const int* __restrict__ counts,
                      const float* __restrict__ sump) {
  if (threadIdx.x == 0 && blockIdx.x == 0) {
    float fc = 0.0f, gs = 0.0f;
    for (int b = 0; b < BB; ++b) {
      fc += (float)counts[b];
      gs += sump[b];
    }
    float F = fc / (float)NROWS;
    float G = gs / (float)NROWS;
    dout[OUT_LOSS] = 1.2f * (5.0f * F * G + (1.0f - F) * (1.0f - G));
  }
}

// ---------------------------------------------------------------------------
__global__ __launch_bounds__(128) void emit(
    const float* __restrict__ x, float* __restrict__ dout,
    const int* __restrict__ sel, const int* __restrict__ counts) {
  const long bid = blockIdx.x;
  const int b = (int)(bid >> 13);
  const int j = (int)(bid & (LL - 1));
  const int cnt = counts[b];
  float4 v = make_float4(0.0f, 0.0f, 0.0f, 0.0f);
  if (j < cnt) {
    const int l = sel[((long)b << 13) + j];
    v = *(const float4*)(x + (((long)b << 13) + l) * 512 + threadIdx.x * 4);
  }
  *(float4*)(dout + OUT_COMP + (((long)b << 13) + j) * 512 + threadIdx.x * 4) = v;
}

// ---------------------------------------------------------------------------
extern "C" void kernel_launch(void* const* d_in, const int* in_sizes, int n_in,
                              void* d_out, int out_size, void* d_ws,
                              size_t ws_size, hipStream_t stream) {
  const float* x = (const float*)d_in[0];
  const float* Wq = (const float*)d_in[1];
  const float* Wk = (const float*)d_in[2];
  float* out = (float*)d_out;
  char* ws = (char*)d_ws;

  int* fixlist = (int*)(ws + WS_FIXLIST);
  int* fixcnt = (int*)(ws + WS_FIXCNT);
  int* counts = (int*)(ws + WS_COUNTS);
  float* sump = (float*)(ws + WS_SUMP);
  int* sel = (int*)(ws + WS_SEL);
  float* ssk = (float*)(ws + WS_SSK);
  float* ssq = (float*)(ws + WS_SSQ);
  float* dotb = (float*)(ws + WS_DOT);
  _Float16* wqh = (_Float16*)(ws + WS_WQH);
  _Float16* wql = (_Float16*)(ws + WS_WQL);
  _Float16* wkh = (_Float16*)(ws + WS_WKH);
  _Float16* wkl = (_Float16*)(ws + WS_WKL);

  // raw k (f16) staged in d_out's compressed region; emit overwrites it.
  _Float16* kbuf = (_Float16*)(out + OUT_COMP);

  wsplit<<<256, 256, 0, stream>>>(Wq, Wk, wqh, wql, wkh, wkl, ssk, ssq, dotb, fixcnt);
  gemm_tile<1><<<2048, 256, 0, stream>>>(x, wkh, wkl, kbuf, ssk, nullptr);
  gemm_tile<2><<<2048, 256, 0, stream>>>(x, wqh, wql, kbuf, ssq, dotb);
  combine<<<NROWS / 256, 256, 0, stream>>>(ssq, ssk, dotb, out, fixlist, fixcnt);
  fixup<<<512, 256, 0, stream>>>(x, Wq, Wk, out, fixlist, fixcnt);
  scanb<<<BB, 256, 0, stream>>>(out, sel, counts, sump);
  lossk<<<1, 64, 0, stream>>>(out, counts, sump);
  emit<<<NROWS, 128, 0, stream>>>(x, out, sel, counts);
}